// Round 11
// baseline (395.468 us; speedup 1.0000x reference)
//
#include <hip/hip_runtime.h>
#include <math.h>

#define NEG_SLOPE 0.2f
#define ESHIFT 8.0f  // constant softmax shift: e=lrelu(s+d) bounded (|e|<~10 << 88), exact after normalization

__device__ __forceinline__ float lrelu(float x) { return x > 0.f ? x : NEG_SLOPE * x; }
__device__ __forceinline__ int clampi(int v, int n) { return min(max(v, 0), n - 1); }
__device__ __forceinline__ unsigned f2bf(float f) {  // fp32 -> bf16 bits, round-to-nearest-even
    unsigned u = __float_as_uint(f);
    return (u + 0x7fffu + ((u >> 16) & 1u)) >> 16;
}

// ---------------- CSR build (once per launch, reused by all 3 layers) ----------------

__global__ void hist(const int* __restrict__ ei, int* __restrict__ deg, int E, int N) {
    const int i = blockIdx.x * blockDim.x + threadIdx.x;
    if (i >= E) return;
    atomicAdd(&deg[clampi(ei[E + i], N)], 1);
}

// Single-dispatch segment allocation: block-local exclusive scan + atomic block base.
// Segment ORDER across blocks is execution-order (irrelevant); per-node contiguity holds.
__global__ void alloc_scan(const int* __restrict__ deg, int* __restrict__ off,
                           int* __restrict__ total, int N) {
    __shared__ int wsum[16];
    __shared__ int base_s;
    const int tid = threadIdx.x, lane = tid & 63, wid = tid >> 6;
    const int i = blockIdx.x * 1024 + tid;
    const int v = (i < N) ? deg[i] : 0;
    int x = v;  // inclusive scan within wave
#pragma unroll
    for (int o = 1; o < 64; o <<= 1) { int y = __shfl_up(x, o); if (lane >= o) x += y; }
    if (lane == 63) wsum[wid] = x;
    __syncthreads();
    if (wid == 0) {
        int ws = (lane < 16) ? wsum[lane] : 0;
#pragma unroll
        for (int o = 1; o < 16; o <<= 1) { int y = __shfl_up(ws, o); if (lane >= o) ws += y; }
        if (lane < 16) wsum[lane] = ws;
    }
    __syncthreads();
    if (tid == 0) base_s = atomicAdd(total, wsum[15]);
    __syncthreads();
    const int wp = wid ? wsum[wid - 1] : 0;
    if (i < N) off[i] = base_s + wp + x - v;
}

// Consumes off: after this, off[n] = end of segment n. aggregate uses start = off[n]-deg[n].
__global__ void scatter(const int* __restrict__ ei, int* __restrict__ off,
                        int* __restrict__ csr, int E, int N) {
    const int i = blockIdx.x * blockDim.x + threadIdx.x;
    if (i >= E) return;
    const int src = clampi(ei[i], N);
    const int dst = clampi(ei[E + i], N);
    csr[atomicAdd(&off[dst], 1)] = src;
}

// ---------------- per-layer kernels ----------------

// Node-tiled GEMM: 64 nodes/block, x-tile in LDS, W streamed with BK=8 register
// prefetch (8 float4 loads in flight -> latency hidden). Writes h as packed bf16
// pairs + per-node attention halves s,d (16-lane shfl reduce).
template <int FIN>
__global__ __launch_bounds__(256) void gemm_sd(
        const float* __restrict__ x, const float* __restrict__ W,
        const float* __restrict__ a_src, const float* __restrict__ a_dst,
        unsigned* __restrict__ hb, float* __restrict__ s, float* __restrict__ d, int N) {
    __shared__ float xs[64 * FIN];
    const int tid = threadIdx.x;
    const int nb = blockIdx.x * 64;
    const int nrows = min(64, N - nb);
    for (int i = tid * 4; i < nrows * FIN; i += 1024)
        *(float4*)&xs[i] = *(const float4*)&x[(size_t)nb * FIN + i];
    __syncthreads();

    const int cg = (tid & 31) * 4;  // flat col base 0..124
    const int ng = tid >> 5;        // node subgroup 0..7
    float acc[8][4];
#pragma unroll
    for (int i = 0; i < 8; ++i)
#pragma unroll
        for (int j = 0; j < 4; ++j) acc[i][j] = 0.f;

    for (int k0 = 0; k0 < FIN; k0 += 8) {
        float4 wv[8];
#pragma unroll
        for (int t = 0; t < 8; ++t) wv[t] = *(const float4*)&W[(k0 + t) * 128 + cg];
#pragma unroll
        for (int t = 0; t < 8; ++t) {
#pragma unroll
            for (int i = 0; i < 8; ++i) {
                const float xv = xs[(ng + 8 * i) * FIN + k0 + t];
                acc[i][0] = fmaf(xv, wv[t].x, acc[i][0]);
                acc[i][1] = fmaf(xv, wv[t].y, acc[i][1]);
                acc[i][2] = fmaf(xv, wv[t].z, acc[i][2]);
                acc[i][3] = fmaf(xv, wv[t].w, acc[i][3]);
            }
        }
    }

    const int head = cg >> 6;
    const int c0 = cg & 63;
    const float4 asv = *(const float4*)&a_src[head * 64 + c0];
    const float4 adv = *(const float4*)&a_dst[head * 64 + c0];
#pragma unroll
    for (int i = 0; i < 8; ++i) {
        const int n = nb + ng + 8 * i;
        if (n < N) {
            hb[(size_t)n * 64 + (cg >> 1) + 0] = f2bf(acc[i][0]) | (f2bf(acc[i][1]) << 16);
            hb[(size_t)n * 64 + (cg >> 1) + 1] = f2bf(acc[i][2]) | (f2bf(acc[i][3]) << 16);
        }
        float ps = acc[i][0] * asv.x + acc[i][1] * asv.y + acc[i][2] * asv.z + acc[i][3] * asv.w;
        float pd = acc[i][0] * adv.x + acc[i][1] * adv.y + acc[i][2] * adv.z + acc[i][3] * adv.w;
#pragma unroll
        for (int o = 1; o < 16; o <<= 1) {
            ps += __shfl_xor(ps, o);
            pd += __shfl_xor(pd, o);
        }
        if ((tid & 15) == 0 && n < N) {
            s[n * 2 + head] = ps;
            d[n * 2 + head] = pd;
        }
    }
}

// One wave per destination node over bf16 h. Lane l owns channel pair (2*(l&31), +1)
// of head (l>>5); one 256B coalesced row load per edge, 8 loads in flight (unroll-8,
// zero-weight self-row padding). Constant-shift softmax. FINAL fuses Wl/sigmoid.
template <bool FINAL>
__global__ void aggregate(const int* __restrict__ csr, const int* __restrict__ offend,
                          const int* __restrict__ deg, const unsigned* __restrict__ hb,
                          const float* __restrict__ s, const float* __restrict__ d,
                          const float* __restrict__ b, float* __restrict__ xout,
                          const float* __restrict__ Wl, const float* __restrict__ bl,
                          float* __restrict__ out, int N) {
    const int lane = threadIdx.x & 63;
    const int n = blockIdx.x * (blockDim.x >> 6) + (threadIdx.x >> 6);
    if (n >= N) return;
    const float2 dn = *(const float2*)&d[2 * n];
    const float2 sn = *(const float2*)&s[2 * n];
    // self-loop
    const float exs0 = __expf(lrelu(sn.x + dn.x) - ESHIFT);
    const float exs1 = __expf(lrelu(sn.y + dn.y) - ESHIFT);
    const unsigned us = hb[(size_t)n * 64 + lane];
    const float wself = (lane < 32) ? exs0 : exs1;
    float ax = wself * __uint_as_float(us << 16);
    float ay = wself * __uint_as_float(us & 0xffff0000u);
    float den0 = (lane == 0) ? exs0 : 0.f;
    float den1 = (lane == 0) ? exs1 : 0.f;

    const int cnt = deg[n];
    const int start = offend[n] - cnt;
    for (int base = 0; base < cnt; base += 64) {
        const int cc = min(cnt - base, 64);
        int srcl = n;  // padding lanes: self row (L1-hot), zero weight
        float ex0 = 0.f, ex1 = 0.f;
        if (lane < cc) {
            srcl = csr[start + base + lane];
            const float2 ss = *(const float2*)&s[2 * srcl];
            ex0 = __expf(lrelu(ss.x + dn.x) - ESHIFT);
            ex1 = __expf(lrelu(ss.y + dn.y) - ESHIFT);
        }
        den0 += ex0;
        den1 += ex1;
        const int rnd = (cc + 7) & ~7;  // unroll-8 with zero-weight padding
        for (int j = 0; j < rnd; j += 8) {
#pragma unroll
            for (int t = 0; t < 8; ++t) {
                const int sj = __shfl(srcl, j + t);
                const float w0 = __shfl(ex0, j + t);
                const float w1 = __shfl(ex1, j + t);
                const float w = (lane < 32) ? w0 : w1;
                const unsigned u = hb[(size_t)sj * 64 + lane];
                ax = fmaf(w, __uint_as_float(u << 16), ax);
                ay = fmaf(w, __uint_as_float(u & 0xffff0000u), ay);
            }
        }
    }
#pragma unroll
    for (int o = 32; o; o >>= 1) {
        den0 += __shfl_xor(den0, o);
        den1 += __shfl_xor(den1, o);
    }
    const float dsel = (lane < 32) ? den0 : den1;
    const float tx = ax / dsel, ty = ay / dsel;
    const float ox = __shfl_xor(tx, 32), oy = __shfl_xor(ty, 32);  // partner head, same channels
    const int c0 = (lane & 31) * 2;
    const float2 bb = *(const float2*)&b[c0];
    float vx = 0.5f * (tx + ox) + bb.x;
    float vy = 0.5f * (ty + oy) + bb.y;
    vx = vx > 0.f ? vx : expm1f(vx);
    vy = vy > 0.f ? vy : expm1f(vy);
    if (!FINAL) {
        if (lane < 32) *(float2*)&xout[(size_t)n * 64 + c0] = make_float2(vx, vy);
    } else {
        const float2 wl = *(const float2*)&Wl[c0];
        float t = (lane < 32) ? (vx * wl.x + vy * wl.y) : 0.f;
#pragma unroll
        for (int o = 32; o; o >>= 1) t += __shfl_down(t, o);
        if (lane == 0) out[n] = 1.f / (1.f + expf(-(t + bl[0])));
    }
}

extern "C" void kernel_launch(void* const* d_in, const int* in_sizes, int n_in,
                              void* d_out, int out_size, void* d_ws, size_t ws_size,
                              hipStream_t stream) {
    const float* X = (const float*)d_in[0];
    const int* ei = (const int*)d_in[1];  // harness delivers integer inputs as int32
    const float* Wm[3] = {(const float*)d_in[3], (const float*)d_in[7], (const float*)d_in[11]};
    const float* As[3] = {(const float*)d_in[4], (const float*)d_in[8], (const float*)d_in[12]};
    const float* Ad[3] = {(const float*)d_in[5], (const float*)d_in[9], (const float*)d_in[13]};
    const float* Bs[3] = {(const float*)d_in[6], (const float*)d_in[10], (const float*)d_in[14]};
    const float* Wl = (const float*)d_in[15];
    const float* bl = (const float*)d_in[16];
    float* out = (float*)d_out;

    const int N = in_sizes[0] / 128;
    const int E = in_sizes[1] / 2;
    const int nb = (N + 1023) / 1024;

    char* w = (char*)d_ws;
    unsigned* hb = (unsigned*)w; w += (size_t)N * 64 * sizeof(unsigned);  // bf16 h, packed pairs
    float* xb = (float*)w;       w += (size_t)N * 64 * sizeof(float);
    float* sA = (float*)w;       w += (size_t)N * 2 * sizeof(float);
    float* dA = (float*)w;       w += (size_t)N * 2 * sizeof(float);
    int* deg = (int*)w;          w += (size_t)(N + 1) * sizeof(int);
    int* total = deg + N;        // zeroed together with deg
    int* off = (int*)w;          w += (size_t)N * sizeof(int);
    int* csr = (int*)w;          w += (size_t)E * sizeof(int);

    // ---- CSR build (graph identical across layers) ----
    hipMemsetAsync(deg, 0, (size_t)(N + 1) * sizeof(int), stream);
    hist<<<(E + 255) / 256, 256, 0, stream>>>(ei, deg, E, N);
    alloc_scan<<<nb, 1024, 0, stream>>>(deg, off, total, N);
    scatter<<<(E + 255) / 256, 256, 0, stream>>>(ei, off, csr, E, N);  // off -> segment ends

    const float* xin = X;
    const int gblk = (N + 63) / 64;
    for (int L = 0; L < 3; ++L) {
        if (L == 0)
            gemm_sd<128><<<gblk, 256, 0, stream>>>(xin, Wm[L], As[L], Ad[L], hb, sA, dA, N);
        else
            gemm_sd<64><<<gblk, 256, 0, stream>>>(xin, Wm[L], As[L], Ad[L], hb, sA, dA, N);
        if (L < 2) {
            aggregate<false><<<(N + 3) / 4, 256, 0, stream>>>(csr, off, deg, hb, sA, dA, Bs[L],
                                                              xb, nullptr, nullptr, nullptr, N);
            xin = xb;
        } else {
            aggregate<true><<<(N + 3) / 4, 256, 0, stream>>>(csr, off, deg, hb, sA, dA, Bs[L],
                                                             nullptr, Wl, bl, out, N);
        }
    }
}

// Round 13
// 383.736 us; speedup vs baseline: 1.0306x; 1.0306x over previous
//
#include <hip/hip_runtime.h>
#include <math.h>

#define NEG_SLOPE 0.2f
#define ESHIFT 8.0f  // constant softmax shift: e=lrelu(s+d) bounded (|e|<~10 << 88), exact after normalization

__device__ __forceinline__ float lrelu(float x) { return x > 0.f ? x : NEG_SLOPE * x; }
__device__ __forceinline__ int clampi(int v, int n) { return min(max(v, 0), n - 1); }
__device__ __forceinline__ unsigned f2bf(float f) {  // fp32 -> bf16 bits, round-to-nearest-even
    unsigned u = __float_as_uint(f);
    return (u + 0x7fffu + ((u >> 16) & 1u)) >> 16;
}

// ---------------- CSR build (once per launch, reused by all 3 layers) ----------------

__global__ void hist(const int* __restrict__ ei, int* __restrict__ deg, int E, int N) {
    const int i = blockIdx.x * blockDim.x + threadIdx.x;
    if (i >= E) return;
    atomicAdd(&deg[clampi(ei[E + i], N)], 1);
}

// Single-dispatch segment allocation: block-local exclusive scan + atomic block base.
// Segment ORDER across blocks is execution-order (irrelevant); per-node contiguity holds.
__global__ void alloc_scan(const int* __restrict__ deg, int* __restrict__ off,
                           int* __restrict__ total, int N) {
    __shared__ int wsum[16];
    __shared__ int base_s;
    const int tid = threadIdx.x, lane = tid & 63, wid = tid >> 6;
    const int i = blockIdx.x * 1024 + tid;
    const int v = (i < N) ? deg[i] : 0;
    int x = v;  // inclusive scan within wave
#pragma unroll
    for (int o = 1; o < 64; o <<= 1) { int y = __shfl_up(x, o); if (lane >= o) x += y; }
    if (lane == 63) wsum[wid] = x;
    __syncthreads();
    if (wid == 0) {
        int ws = (lane < 16) ? wsum[lane] : 0;
#pragma unroll
        for (int o = 1; o < 16; o <<= 1) { int y = __shfl_up(ws, o); if (lane >= o) ws += y; }
        if (lane < 16) wsum[lane] = ws;
    }
    __syncthreads();
    if (tid == 0) base_s = atomicAdd(total, wsum[15]);
    __syncthreads();
    const int wp = wid ? wsum[wid - 1] : 0;
    if (i < N) off[i] = base_s + wp + x - v;
}

// Consumes off: after this, off[n] = end of segment n. aggregate uses start = off[n]-deg[n].
__global__ void scatter(const int* __restrict__ ei, int* __restrict__ off,
                        int* __restrict__ csr, int E, int N) {
    const int i = blockIdx.x * blockDim.x + threadIdx.x;
    if (i >= E) return;
    const int src = clampi(ei[i], N);
    const int dst = clampi(ei[E + i], N);
    const int pos = atomicAdd(&off[dst], 1);
    __builtin_nontemporal_store(src, &csr[pos]);
}

// ---------------- per-layer kernels ----------------

// Node-tiled GEMM: 64 nodes/block, x-tile in LDS read as float4 (b128, 4x fewer LDS
// insts), W streamed with BK=4 register prefetch. Writes h as packed bf16 pairs +
// per-node attention halves s,d (16-lane shfl reduce).
template <int FIN>
__global__ __launch_bounds__(256) void gemm_sd(
        const float* __restrict__ x, const float* __restrict__ W,
        const float* __restrict__ a_src, const float* __restrict__ a_dst,
        unsigned* __restrict__ hb, float* __restrict__ s, float* __restrict__ d, int N) {
    __shared__ float xs[64 * FIN];
    const int tid = threadIdx.x;
    const int nb = blockIdx.x * 64;
    const int nrows = min(64, N - nb);
    for (int i = tid * 4; i < nrows * FIN; i += 1024)
        *(float4*)&xs[i] = *(const float4*)&x[(size_t)nb * FIN + i];
    __syncthreads();

    const int cg = (tid & 31) * 4;  // flat col base 0..124
    const int ng = tid >> 5;        // node subgroup 0..7
    float acc[8][4];
#pragma unroll
    for (int i = 0; i < 8; ++i)
#pragma unroll
        for (int j = 0; j < 4; ++j) acc[i][j] = 0.f;

    for (int k0 = 0; k0 < FIN; k0 += 4) {
        float4 wv[4];
#pragma unroll
        for (int t = 0; t < 4; ++t) wv[t] = *(const float4*)&W[(k0 + t) * 128 + cg];
        float4 xv[8];
#pragma unroll
        for (int i = 0; i < 8; ++i) xv[i] = *(const float4*)&xs[(ng + 8 * i) * FIN + k0];
#pragma unroll
        for (int t = 0; t < 4; ++t) {
#pragma unroll
            for (int i = 0; i < 8; ++i) {
                const float xf = ((const float*)&xv[i])[t];  // static index after unroll
                acc[i][0] = fmaf(xf, wv[t].x, acc[i][0]);
                acc[i][1] = fmaf(xf, wv[t].y, acc[i][1]);
                acc[i][2] = fmaf(xf, wv[t].z, acc[i][2]);
                acc[i][3] = fmaf(xf, wv[t].w, acc[i][3]);
            }
        }
    }

    const int head = cg >> 6;
    const int c0 = cg & 63;
    const float4 asv = *(const float4*)&a_src[head * 64 + c0];
    const float4 adv = *(const float4*)&a_dst[head * 64 + c0];
#pragma unroll
    for (int i = 0; i < 8; ++i) {
        const int n = nb + ng + 8 * i;
        if (n < N) {
            hb[(size_t)n * 64 + (cg >> 1) + 0] = f2bf(acc[i][0]) | (f2bf(acc[i][1]) << 16);
            hb[(size_t)n * 64 + (cg >> 1) + 1] = f2bf(acc[i][2]) | (f2bf(acc[i][3]) << 16);
        }
        float ps = acc[i][0] * asv.x + acc[i][1] * asv.y + acc[i][2] * asv.z + acc[i][3] * asv.w;
        float pd = acc[i][0] * adv.x + acc[i][1] * adv.y + acc[i][2] * adv.z + acc[i][3] * adv.w;
#pragma unroll
        for (int o = 1; o < 16; o <<= 1) {
            ps += __shfl_xor(ps, o);
            pd += __shfl_xor(pd, o);
        }
        if ((tid & 15) == 0 && n < N) {
            s[n * 2 + head] = ps;
            d[n * 2 + head] = pd;
        }
    }
}

// One wave per destination node over bf16 h. Scalar phase packs per-edge
// {src, bf16(ex1)|bf16(ex0)} into wave-private LDS (no shfl broadcasts: inner loop
// does 1 uniform ds_read_b64 + shift/and weight select + one 256B row load + 2 FMA).
// Constant-shift softmax. FINAL fuses Wl/sigmoid.
template <bool FINAL>
__global__ void aggregate(const int* __restrict__ csr, const int* __restrict__ offend,
                          const int* __restrict__ deg, const unsigned* __restrict__ hb,
                          const float* __restrict__ s, const float* __restrict__ d,
                          const float* __restrict__ b, float* __restrict__ xout,
                          const float* __restrict__ Wl, const float* __restrict__ bl,
                          float* __restrict__ out, int N) {
    __shared__ unsigned long long est[4][64];  // per-wave edge metadata
    const int lane = threadIdx.x & 63;
    const int wid = threadIdx.x >> 6;
    const int n = blockIdx.x * (blockDim.x >> 6) + wid;
    if (n >= N) return;
    const unsigned shamt = (lane < 32) ? 16u : 0u;  // weight select: (wp<<shamt)&hi16
    const float2 dn = *(const float2*)&d[2 * n];
    const float2 sn = *(const float2*)&s[2 * n];
    // self-loop
    const float exs0 = __expf(lrelu(sn.x + dn.x) - ESHIFT);
    const float exs1 = __expf(lrelu(sn.y + dn.y) - ESHIFT);
    const unsigned us = hb[(size_t)n * 64 + lane];
    const float wself = (lane < 32) ? exs0 : exs1;
    float ax = wself * __uint_as_float(us << 16);
    float ay = wself * __uint_as_float(us & 0xffff0000u);
    float den0 = (lane == 0) ? exs0 : 0.f;
    float den1 = (lane == 0) ? exs1 : 0.f;

    const int cnt = deg[n];
    const int start = offend[n] - cnt;
    for (int base = 0; base < cnt; base += 64) {
        const int cc = min(cnt - base, 64);
        int srcl = n;  // padding: self row (cached), zero weight
        float ex0 = 0.f, ex1 = 0.f;
        if (lane < cc) {
            srcl = csr[start + base + lane];
            const float2 ss = *(const float2*)&s[2 * srcl];
            ex0 = __expf(lrelu(ss.x + dn.x) - ESHIFT);
            ex1 = __expf(lrelu(ss.y + dn.y) - ESHIFT);
        }
        den0 += ex0;
        den1 += ex1;
        est[wid][lane] = ((unsigned long long)((f2bf(ex1) << 16) | f2bf(ex0)) << 32) | (unsigned)srcl;
        // same-wave LDS write->read: DS ops are in-order per wave; compiler inserts lgkmcnt
        const int rnd = (cc + 7) & ~7;  // unroll-8 with zero-weight padding
        for (int j = 0; j < rnd; j += 8) {
#pragma unroll
            for (int t = 0; t < 8; ++t) {
                const unsigned long long v = est[wid][j + t];  // uniform addr -> broadcast
                const int sj = (int)(unsigned)v;
                const unsigned wp = (unsigned)(v >> 32);
                const float w = __uint_as_float((wp << shamt) & 0xffff0000u);
                const unsigned u = hb[(size_t)sj * 64 + lane];
                ax = fmaf(w, __uint_as_float(u << 16), ax);
                ay = fmaf(w, __uint_as_float(u & 0xffff0000u), ay);
            }
        }
    }
#pragma unroll
    for (int o = 32; o; o >>= 1) {
        den0 += __shfl_xor(den0, o);
        den1 += __shfl_xor(den1, o);
    }
    const float dsel = (lane < 32) ? den0 : den1;
    const float tx = ax / dsel, ty = ay / dsel;
    const float ox = __shfl_xor(tx, 32), oy = __shfl_xor(ty, 32);  // partner head, same channels
    const int c0 = (lane & 31) * 2;
    const float2 bb = *(const float2*)&b[c0];
    float vx = 0.5f * (tx + ox) + bb.x;
    float vy = 0.5f * (ty + oy) + bb.y;
    vx = vx > 0.f ? vx : expm1f(vx);
    vy = vy > 0.f ? vy : expm1f(vy);
    if (!FINAL) {
        if (lane < 32) *(float2*)&xout[(size_t)n * 64 + c0] = make_float2(vx, vy);
    } else {
        const float2 wl = *(const float2*)&Wl[c0];
        float t = (lane < 32) ? (vx * wl.x + vy * wl.y) : 0.f;
#pragma unroll
        for (int o = 32; o; o >>= 1) t += __shfl_down(t, o);
        if (lane == 0) out[n] = 1.f / (1.f + expf(-(t + bl[0])));
    }
}

extern "C" void kernel_launch(void* const* d_in, const int* in_sizes, int n_in,
                              void* d_out, int out_size, void* d_ws, size_t ws_size,
                              hipStream_t stream) {
    const float* X = (const float*)d_in[0];
    const int* ei = (const int*)d_in[1];  // harness delivers integer inputs as int32
    const float* Wm[3] = {(const float*)d_in[3], (const float*)d_in[7], (const float*)d_in[11]};
    const float* As[3] = {(const float*)d_in[4], (const float*)d_in[8], (const float*)d_in[12]};
    const float* Ad[3] = {(const float*)d_in[5], (const float*)d_in[9], (const float*)d_in[13]};
    const float* Bs[3] = {(const float*)d_in[6], (const float*)d_in[10], (const float*)d_in[14]};
    const float* Wl = (const float*)d_in[15];
    const float* bl = (const float*)d_in[16];
    float* out = (float*)d_out;

    const int N = in_sizes[0] / 128;
    const int E = in_sizes[1] / 2;
    const int nb = (N + 1023) / 1024;

    char* w = (char*)d_ws;
    unsigned* hb = (unsigned*)w; w += (size_t)N * 64 * sizeof(unsigned);  // bf16 h, packed pairs
    float* xb = (float*)w;       w += (size_t)N * 64 * sizeof(float);
    float* sA = (float*)w;       w += (size_t)N * 2 * sizeof(float);
    float* dA = (float*)w;       w += (size_t)N * 2 * sizeof(float);
    int* deg = (int*)w;          w += (size_t)(N + 1) * sizeof(int);
    int* total = deg + N;        // zeroed together with deg
    int* off = (int*)w;          w += (size_t)N * sizeof(int);
    int* csr = (int*)w;          w += (size_t)E * sizeof(int);

    // ---- CSR build (graph identical across layers) ----
    hipMemsetAsync(deg, 0, (size_t)(N + 1) * sizeof(int), stream);
    hist<<<(E + 255) / 256, 256, 0, stream>>>(ei, deg, E, N);
    alloc_scan<<<nb, 1024, 0, stream>>>(deg, off, total, N);
    scatter<<<(E + 255) / 256, 256, 0, stream>>>(ei, off, csr, E, N);  // off -> segment ends

    const float* xin = X;
    const int gblk = (N + 63) / 64;
    for (int L = 0; L < 3; ++L) {
        if (L == 0)
            gemm_sd<128><<<gblk, 256, 0, stream>>>(xin, Wm[L], As[L], Ad[L], hb, sA, dA, N);
        else
            gemm_sd<64><<<gblk, 256, 0, stream>>>(xin, Wm[L], As[L], Ad[L], hb, sA, dA, N);
        if (L < 2) {
            aggregate<false><<<(N + 3) / 4, 256, 0, stream>>>(csr, off, deg, hb, sA, dA, Bs[L],
                                                              xb, nullptr, nullptr, nullptr, N);
            xin = xb;
        } else {
            aggregate<true><<<(N + 3) / 4, 256, 0, stream>>>(csr, off, deg, hb, sA, dA, Bs[L],
                                                             nullptr, Wl, bl, out, N);
        }
    }
}